// Round 5
// baseline (152.987 us; speedup 1.0000x reference)
//
#include <hip/hip_runtime.h>
#include <stdint.h>

#define B   256
#define IU  8      // in_units (i)
#define JC  1152   // in_channels (j)
#define NN  10     // num_units (n)
#define UU  16     // unit_size (u)
#define NU  160    // NN*UU
#define JN  11520  // JC*NN
#define WROW 1280  // NN*UU*IU, floats per j in W
#define NP  9216   // IU*JC, x row length
#define KB  36     // k-split count (32 j per slice, 2 chunks of 16)

typedef short bf16x8 __attribute__((ext_vector_type(8)));
typedef float f32x4  __attribute__((ext_vector_type(4)));

__device__ __forceinline__ short f2bf(float f) {
    union { float f; uint32_t u; } cv; cv.f = f;
    uint32_t u = cv.u;
    uint32_t r = u + 0x7fffu + ((u >> 16) & 1u);
    return (short)(r >> 16);
}
__device__ __forceinline__ float bf2f(short h) {
    union { uint32_t u; float f; } cv; cv.u = ((uint32_t)(unsigned short)h) << 16;
    return cv.f;
}
__device__ __forceinline__ uint32_t bfbits(float f) {
    union { float f; uint32_t u; } cv; cv.f = f;
    return (cv.u + 0x7fffu + ((cv.u >> 16) & 1u)) >> 16;
}
__device__ __forceinline__ uint32_t pk2(float a, float b) {
    return bfbits(a) | (bfbits(b) << 16);
}
__device__ __forceinline__ void gload16(const void* g, void* l) {
    __builtin_amdgcn_global_load_lds(
        (const __attribute__((address_space(1))) void*)g,
        (__attribute__((address_space(3))) void*)l, 16, 0, 0);
}

// ---------------- prep: W->bf16 (linear), x->bf16 transposed [j][b*8+i] --
// grid 1296: blocks 0..575 transpose x (64x64 tiles), 576..1295 convert W.
// Block 0 zeroes the expsum banks (ws is re-poisoned before every replay).
__global__ void __launch_bounds__(256)
k_prep(const float* __restrict__ xg, const float* __restrict__ wg,
       short* __restrict__ wbf, short* __restrict__ xbf,
       float* __restrict__ expsum) {
    const int bid = blockIdx.x, tid = threadIdx.x;
    if (bid == 0 && tid < 32) expsum[tid] = 0.f;
    if (bid < 576) {
        // x viewed as [2048 r][1152 j], r = b*8+i; out xbf[j][r]
        const int jt = bid % 18, rt = bid / 18;
        const int j0 = jt * 64, r0 = rt * 64;
        __shared__ short T[64][72];
        #pragma unroll
        for (int p = 0; p < 4; ++p) {
            int idx = tid + 256 * p;        // 0..1023
            int row = idx >> 4;             // 0..63
            int c4  = (idx & 15) * 4;       // 0..60
            float4 xv = *reinterpret_cast<const float4*>(
                &xg[(size_t)(r0 + row) * JC + j0 + c4]);
            T[c4+0][row] = f2bf(xv.x);
            T[c4+1][row] = f2bf(xv.y);
            T[c4+2][row] = f2bf(xv.z);
            T[c4+3][row] = f2bf(xv.w);
        }
        __syncthreads();
        #pragma unroll
        for (int p = 0; p < 2; ++p) {
            int idx = tid + 256 * p;        // 0..511
            int jl = idx >> 3;              // 0..63
            int r8 = (idx & 7) * 8;         // 0..56
            uint4 d = *reinterpret_cast<const uint4*>(&T[jl][r8]);
            *reinterpret_cast<uint4*>(&xbf[(size_t)(j0 + jl) * 2048 + r0 + r8]) = d;
        }
    } else {
        const int b2 = bid - 576;           // 0..719, 2048 floats each
        size_t base = (size_t)b2 * 2048 + (size_t)tid * 8;
        float4 f0 = *reinterpret_cast<const float4*>(&wg[base]);
        float4 f1 = *reinterpret_cast<const float4*>(&wg[base + 4]);
        uint4 d;
        d.x = pk2(f0.x, f0.y); d.y = pk2(f0.z, f0.w);
        d.z = pk2(f1.x, f1.y); d.w = pk2(f1.z, f1.w);
        *reinterpret_cast<uint4*>(&wbf[base]) = d;
    }
}

// ---------------- pass 1 MFMA GEMM: s_raw = x * (e*W)^T (unnormalized) ---
// grid (KB=36 k-splits of 32 j, 8 m-tiles of 32 b) = 288 blocks; 4 waves.
// Staging is pure global_load_lds DMA; 16-j chunks -> only 4 barriers.
// Softmax normalization (1/Z_n, or 1/JC at t=0) is applied in k_reduce_s.
__global__ void __launch_bounds__(256, 2)
k_gemm1(const short* __restrict__ xbf, const short* __restrict__ wbf,
        float* __restrict__ s_part) {
    const int kb = blockIdx.x, mt = blockIdx.y;
    const int tid = threadIdx.x;
    const int wv = tid >> 6, lane = tid & 63;
    const int q = lane >> 4, l16 = lane & 15;
    const int b0 = mt * 32;
    const int jb0 = kb * 32;
    const int mfrag = wv >> 1;          // 0..1
    const int ntb = (wv & 1) * 5;       // 0 or 5

    __shared__ __align__(16) short As[16 * 32 * 8];   // 8 KB  [jj][bl][ii]
    __shared__ __align__(16) short Bs[16 * 160 * 8];  // 40 KB [jj][nu][ii]

    f32x4 acc[5];
    #pragma unroll
    for (int nt = 0; nt < 5; ++nt) acc[nt] = (f32x4){0.f, 0.f, 0.f, 0.f};

    for (int jc = 0; jc < 2; ++jc) {
        const int j0 = jb0 + jc * 16;
        __syncthreads();
        // As: xbf[j0+jj][(b0+bl)*8 ..+8] -> As[jj][bl][ii]; 2 DMA/thread
        #pragma unroll
        for (int p = 0; p < 2; ++p) {
            int idx = tid + 256 * p;    // 0..511 = jj*32+bl
            gload16(xbf + ((size_t)(j0 + (idx >> 5)) * 2048
                           + (size_t)(b0 + (idx & 31)) * 8),
                    &As[idx * 8]);
        }
        // Bs: wbf rows contiguous: src = wbf + j0*1280 + ridx*8
        const short* wsrc = wbf + (size_t)j0 * WROW;
        #pragma unroll
        for (int p = 0; p < 10; ++p) {
            int ridx = tid + 256 * p;   // 0..2559 = jj*160+nu
            gload16(wsrc + (size_t)ridx * 8, &Bs[ridx * 8]);
        }
        __syncthreads();
        #pragma unroll
        for (int s = 0; s < 4; ++s) {
            int jj = s * 4 + q;
            bf16x8 av = *reinterpret_cast<const bf16x8*>(
                &As[(jj * 32 + mfrag * 16 + l16) << 3]);
            #pragma unroll
            for (int nt = 0; nt < 5; ++nt) {
                bf16x8 bv = *reinterpret_cast<const bf16x8*>(
                    &Bs[(jj * 160 + (ntb + nt) * 16 + l16) << 3]);
                acc[nt] = __builtin_amdgcn_mfma_f32_16x16x32_bf16(av, bv, acc[nt], 0, 0, 0);
            }
        }
    }
    float* dst = s_part + (size_t)(kb * 8 + mt) * 5120;
    #pragma unroll
    for (int nt = 0; nt < 5; ++nt)
        #pragma unroll
        for (int reg = 0; reg < 4; ++reg)
            dst[(mfrag * 16 + q * 4 + reg) * 160 + (ntb + nt) * 16 + l16] = acc[nt][reg];
}

// ---------------- fused reduce (36 slices) + normalize + squash ----------
__global__ void __launch_bounds__(320, 2)
k_reduce_s(const float* __restrict__ s_part, float* __restrict__ vdst,
           const float* __restrict__ expsum, int t0) {
    const int b = blockIdx.x, tid = threadIdx.x;
    const int t = tid % 160, kq = tid / 160;
    const int mt = b >> 5, bl = b & 31;
    const size_t off = (size_t)mt * 5120 + bl * 160 + t;

    __shared__ float invn[NN];
    if (tid < NN) invn[tid] = t0 ? (1.f / (float)JC) : 1.f / expsum[tid];

    float s = 0.f;
    for (int r = 0; r < 18; ++r)
        s += s_part[(size_t)(kq * 18 + r) * 40960 + off];

    __shared__ float red[2][160];
    __shared__ float sv[NU];
    __shared__ float fb[UU];
    red[kq][t] = s;
    __syncthreads();
    if (tid < NU) sv[tid] = (red[0][tid] + red[1][tid]) * invn[tid >> 4];
    __syncthreads();
    if (tid < UU) {
        float m = 0.f;
        #pragma unroll
        for (int n = 0; n < NN; ++n) { float z = sv[n*16 + tid]; m = fmaf(z, z, m); }
        fb[tid] = sqrtf(m) / (1.f + m);
    }
    __syncthreads();
    if (tid < NU)
        vdst[(size_t)b * NU + tid] = sv[tid] * fb[tid & 15];
}

// ---------------- fused routing: G-tile in LDS + d + softmax + e*W -------
// Block (jt 0..35, ng 0..4): j-range 32, n-range 2, full K=256 (batch).
// Staging vectorized (float4) and XOR-swizzled (col ^= kc) to kill the
// 16-way ds_write bank conflict; MFMA reads apply the same swizzle.
__global__ void __launch_bounds__(256)
k_route(const float* __restrict__ vg, const float* __restrict__ xg,
        const float* __restrict__ wg, float* __restrict__ blog,
        short* __restrict__ wbf, float* __restrict__ expsum, int t0) {
    const int jt = blockIdx.x, ng = blockIdx.y;
    const int j0 = jt * 32, n0 = ng * 2, m0 = n0 * 16;
    const int tid = threadIdx.x;
    const int wv = tid >> 6, lane = tid & 63;
    const int q = lane >> 4, l16 = lane & 15;
    const int mtl = wv >> 1, ntc = wv & 1;   // wave quadrant (m-tile, j-tile)

    __shared__ __align__(16) short Ash[8192], Asl[8192]; // [ks4][kc8][ml32^kc][blo8]
    __shared__ __align__(16) short Bsh[8192], Bsl[8192]; // [ks4][kc8][jl32^kc][blo8]
    __shared__ float Gt[32 * 32];
    __shared__ float red[256];
    __shared__ float esh[64];

    // stage v[0..255, m0..m0+32] hi/lo, float4 loads, swizzled LDS writes
    #pragma unroll
    for (int p = 0; p < 8; ++p) {
        int idx = tid + 256 * p;        // 0..2047
        int b = idx >> 3, c4 = (idx & 7) * 4;
        float4 vv = *reinterpret_cast<const float4*>(&vg[(size_t)b * NU + m0 + c4]);
        int kc = (b >> 3) & 7;
        int abase = (b >> 6) * 2048 + kc * 256 + (b & 7);
        #pragma unroll
        for (int e = 0; e < 4; ++e) {
            float f = (e == 0) ? vv.x : (e == 1) ? vv.y : (e == 2) ? vv.z : vv.w;
            short hi = f2bf(f);
            short lo = f2bf(f - bf2f(hi));
            int a = abase + (((c4 + e) ^ kc) << 3);
            Ash[a] = hi; Asl[a] = lo;
        }
    }

    float part = 0.f;
    const int jl_c = tid & 31, rr = tid >> 5;
    const int nn_c = rr >> 2, uq = rr & 3;

    for (int i = 0; i < 8; ++i) {
        __syncthreads();                 // Bs free (prev mfma done), Gt free
        // stage x[0..255][i][j0..j0+32] hi/lo: one 128B row per thread
        {
            int b = tid;
            const float4* xp = reinterpret_cast<const float4*>(
                &xg[(size_t)b * NP + i * JC + j0]);
            int kc = (b >> 3) & 7;
            int abase = (b >> 6) * 2048 + kc * 256 + (b & 7);
            #pragma unroll
            for (int c = 0; c < 8; ++c) {
                float4 xv = xp[c];
                #pragma unroll
                for (int e = 0; e < 4; ++e) {
                    float f = (e == 0) ? xv.x : (e == 1) ? xv.y : (e == 2) ? xv.z : xv.w;
                    short hi = f2bf(f);
                    short lo = f2bf(f - bf2f(hi));
                    int a = abase + (((c * 4 + e) ^ kc) << 3);
                    Bsh[a] = hi; Bsl[a] = lo;
                }
            }
        }
        __syncthreads();
        f32x4 acc = (f32x4){0.f, 0.f, 0.f, 0.f};
        #pragma unroll
        for (int ks = 0; ks < 4; ++ks)
            #pragma unroll
            for (int s = 0; s < 2; ++s) {
                int kc = s * 4 + q;
                const int ai = ks * 2048 + kc * 256
                             + (((mtl * 16 + l16) ^ kc) << 3);
                const int bi = ks * 2048 + kc * 256
                             + (((ntc * 16 + l16) ^ kc) << 3);
                bf16x8 ah = *reinterpret_cast<const bf16x8*>(&Ash[ai]);
                bf16x8 al = *reinterpret_cast<const bf16x8*>(&Asl[ai]);
                bf16x8 bh = *reinterpret_cast<const bf16x8*>(&Bsh[bi]);
                bf16x8 bl = *reinterpret_cast<const bf16x8*>(&Bsl[bi]);
                acc = __builtin_amdgcn_mfma_f32_16x16x32_bf16(ah, bh, acc, 0, 0, 0);
                acc = __builtin_amdgcn_mfma_f32_16x16x32_bf16(ah, bl, acc, 0, 0, 0);
                acc = __builtin_amdgcn_mfma_f32_16x16x32_bf16(al, bh, acc, 0, 0, 0);
            }
        __syncthreads();                 // prior contract finished reading Gt
        #pragma unroll
        for (int r = 0; r < 4; ++r)      // C-layout: row=q*4+r, col=l16
            Gt[(mtl * 16 + q * 4 + r) * 32 + ntc * 16 + l16] = acc[r];
        __syncthreads();
        {   // contract: thread = (jl, nn, uq); d += G[nn*16+u][jl]*W[j,n,u,i]
            const float* wrow = wg + (size_t)(j0 + jl_c) * WROW
                              + (n0 + nn_c) * 128 + i;
            #pragma unroll
            for (int k = 0; k < 4; ++k)
                part = fmaf(Gt[(nn_c * 16 + uq * 4 + k) * 32 + jl_c],
                            wrow[(uq * 4 + k) * 8], part);
        }
    }
    // fold partials over uq
    red[((rr >> 2) * 32 + jl_c) * 4 + (rr & 3)] = part;
    __syncthreads();
    if (tid < 64) {                      // wave 0: finalize d, blog, exp
        int jl = tid & 31, nn = tid >> 5;
        int ri = (nn * 32 + jl) * 4;
        float d = (red[ri] + red[ri + 1] + red[ri + 2] + red[ri + 3])
                  * (1.f / (float)B);
        int bi = (j0 + jl) * NN + n0 + nn;
        float nb = t0 ? d : (blog[bi] + d);
        blog[bi] = nb;
        float e = __expf(nb);
        esh[jl * 2 + nn] = e;
        float ssum = e;
        ssum += __shfl_xor(ssum, 1);  ssum += __shfl_xor(ssum, 2);
        ssum += __shfl_xor(ssum, 4);  ssum += __shfl_xor(ssum, 8);
        ssum += __shfl_xor(ssum, 16);
        if ((tid & 31) == 0) atomicAdd(&expsum[n0 + nn], ssum);
    }
    __syncthreads();
    {   // wbf[j0+row][n0*128 + seg*32 ..+32] = bf16(e * W), reg-direct
        int row = tid >> 3, seg = tid & 7;
        float e = esh[row * 2 + (seg >> 2)];
        const float4* wp = reinterpret_cast<const float4*>(
            wg + (size_t)(j0 + row) * WROW + n0 * 128 + seg * 32);
        short* dst = wbf + (size_t)(j0 + row) * WROW + n0 * 128 + seg * 32;
        #pragma unroll
        for (int k2 = 0; k2 < 4; ++k2) {
            float4 f0 = wp[k2 * 2], f1 = wp[k2 * 2 + 1];
            uint4 dd;
            dd.x = pk2(f0.x * e, f0.y * e); dd.y = pk2(f0.z * e, f0.w * e);
            dd.z = pk2(f1.x * e, f1.y * e); dd.w = pk2(f1.z * e, f1.w * e);
            *reinterpret_cast<uint4*>(&dst[k2 * 8]) = dd;
        }
    }
}

extern "C" void kernel_launch(void* const* d_in, const int* in_sizes, int n_in,
                              void* d_out, int out_size, void* d_ws, size_t ws_size,
                              hipStream_t stream) {
    const float* x = (const float*)d_in[0];
    const float* w = (const float*)d_in[1];
    float* out = (float*)d_out;

    float* ws     = (float*)d_ws;
    float* blog   = ws;                           // 11520 f
    float* expsum = blog + JN;                    // 32 f (2 banks of 16)
    float* v      = expsum + 32;                  // 40960 f
    short* wbf    = (short*)(v + (size_t)B * NU); // 1,474,560 bf16 (2.95 MB)
    short* xbf    = wbf + (size_t)JC * WROW;      // 2,359,296 bf16 (4.72 MB)
    float* s_part = (float*)(xbf + (size_t)JC * 2048); // 36*40960 f (5.9 MB)
    // total ≈ 13.8 MB

    k_prep<<<1296, 256, 0, stream>>>(x, w, wbf, xbf, expsum);
    for (int t = 0; t < 3; ++t) {
        k_gemm1<<<dim3(KB, 8), 256, 0, stream>>>(xbf, wbf, s_part);
        k_reduce_s<<<B, 320, 0, stream>>>(
            s_part, (t == 2) ? out : v,
            expsum + ((t == 0) ? 0 : (t - 1) * 16), (t == 0) ? 1 : 0);
        if (t < 2)
            k_route<<<dim3(36, 5), 256, 0, stream>>>(
                v, x, w, blog, wbf, expsum + t * 16, (t == 0) ? 1 : 0);
    }
}

// Round 6
// 142.008 us; speedup vs baseline: 1.0773x; 1.0773x over previous
//
#include <hip/hip_runtime.h>
#include <stdint.h>

#define B   256
#define IU  8      // in_units (i)
#define JC  1152   // in_channels (j)
#define NN  10     // num_units (n)
#define UU  16     // unit_size (u)
#define NU  160    // NN*UU
#define JN  11520  // JC*NN
#define WROW 1280  // NN*UU*IU, floats per j in W
#define NP  9216   // IU*JC, x row length
#define KB  36     // k-split count (32 j per slice, 4 chunks of 8)

typedef short bf16x8 __attribute__((ext_vector_type(8)));
typedef float f32x4  __attribute__((ext_vector_type(4)));

__device__ __forceinline__ short f2bf(float f) {
    union { float f; uint32_t u; } cv; cv.f = f;
    uint32_t u = cv.u;
    uint32_t r = u + 0x7fffu + ((u >> 16) & 1u);
    return (short)(r >> 16);
}
__device__ __forceinline__ float bf2f(short h) {
    union { uint32_t u; float f; } cv; cv.u = ((uint32_t)(unsigned short)h) << 16;
    return cv.f;
}
__device__ __forceinline__ uint32_t bfbits(float f) {
    union { float f; uint32_t u; } cv; cv.f = f;
    return (cv.u + 0x7fffu + ((cv.u >> 16) & 1u)) >> 16;
}
__device__ __forceinline__ uint32_t pk2(float a, float b) {
    return bfbits(a) | (bfbits(b) << 16);
}
__device__ __forceinline__ void gload16(const void* g, void* l) {
    __builtin_amdgcn_global_load_lds(
        (const __attribute__((address_space(1))) void*)g,
        (__attribute__((address_space(3))) void*)l, 16, 0, 0);
}

// ---------------- prep: W->bf16 (linear), x->bf16 transposed [j][b*8+i] --
// grid 1296: blocks 0..575 transpose x (64x64 tiles), 576..1295 convert W.
// Block 0 zeroes the expsum banks (ws is re-poisoned before every replay).
__global__ void __launch_bounds__(256)
k_prep(const float* __restrict__ xg, const float* __restrict__ wg,
       short* __restrict__ wbf, short* __restrict__ xbf,
       float* __restrict__ expsum) {
    const int bid = blockIdx.x, tid = threadIdx.x;
    if (bid == 0 && tid < 32) expsum[tid] = 0.f;
    if (bid < 576) {
        // x viewed as [2048 r][1152 j], r = b*8+i; out xbf[j][r]
        const int jt = bid % 18, rt = bid / 18;
        const int j0 = jt * 64, r0 = rt * 64;
        __shared__ short T[64][72];
        #pragma unroll
        for (int p = 0; p < 4; ++p) {
            int idx = tid + 256 * p;        // 0..1023
            int row = idx >> 4;             // 0..63
            int c4  = (idx & 15) * 4;       // 0..60
            float4 xv = *reinterpret_cast<const float4*>(
                &xg[(size_t)(r0 + row) * JC + j0 + c4]);
            T[c4+0][row] = f2bf(xv.x);
            T[c4+1][row] = f2bf(xv.y);
            T[c4+2][row] = f2bf(xv.z);
            T[c4+3][row] = f2bf(xv.w);
        }
        __syncthreads();
        #pragma unroll
        for (int p = 0; p < 2; ++p) {
            int idx = tid + 256 * p;        // 0..511
            int jl = idx >> 3;              // 0..63
            int r8 = (idx & 7) * 8;         // 0..56
            uint4 d = *reinterpret_cast<const uint4*>(&T[jl][r8]);
            *reinterpret_cast<uint4*>(&xbf[(size_t)(j0 + jl) * 2048 + r0 + r8]) = d;
        }
    } else {
        const int b2 = bid - 576;           // 0..719, 2048 floats each
        size_t base = (size_t)b2 * 2048 + (size_t)tid * 8;
        float4 f0 = *reinterpret_cast<const float4*>(&wg[base]);
        float4 f1 = *reinterpret_cast<const float4*>(&wg[base + 4]);
        uint4 d;
        d.x = pk2(f0.x, f0.y); d.y = pk2(f0.z, f0.w);
        d.z = pk2(f1.x, f1.y); d.w = pk2(f1.z, f1.w);
        *reinterpret_cast<uint4*>(&wbf[base]) = d;
    }
}

// ---------------- pass 1 MFMA GEMM: s_raw = x * (e*W)^T (unnormalized) ---
// grid (KB=36 k-splits of 32 j, 8 m-tiles of 32 b) = 288 blocks; 4 waves.
// Staging is pure global_load_lds DMA from prepped bf16 operands.
// Softmax normalization (1/Z_n, or 1/JC at t=0) is applied in k_reduce_s.
__global__ void __launch_bounds__(256, 2)
k_gemm1(const short* __restrict__ xbf, const short* __restrict__ wbf,
        float* __restrict__ s_part) {
    const int kb = blockIdx.x, mt = blockIdx.y;
    const int tid = threadIdx.x;
    const int wv = tid >> 6, lane = tid & 63;
    const int q = lane >> 4, l16 = lane & 15;
    const int b0 = mt * 32;
    const int jb0 = kb * 32;
    const int mfrag = wv >> 1;          // 0..1
    const int ntb = (wv & 1) * 5;       // 0 or 5

    __shared__ __align__(16) short As[8 * 32 * 8];   // 4 KB  [jj][bl][ii]
    __shared__ __align__(16) short Bs[8 * 160 * 8];  // 20 KB [jj][nu][ii]

    f32x4 acc[5];
    #pragma unroll
    for (int nt = 0; nt < 5; ++nt) acc[nt] = (f32x4){0.f, 0.f, 0.f, 0.f};

    for (int jc = 0; jc < 4; ++jc) {
        const int j0 = jb0 + jc * 8;
        __syncthreads();
        // As: xbf[j0+jj][ (b0+bl)*8 .. +8 ] -> As[jj][bl][ii], 1 DMA/thread
        gload16(xbf + ((size_t)(j0 + (tid >> 5)) * 2048 + (size_t)(b0 + (tid & 31)) * 8),
                &As[tid * 8]);
        // Bs: wbf rows contiguous: src = wbf + j0*1280 + ridx*8
        const short* wsrc = wbf + (size_t)j0 * WROW;
        #pragma unroll
        for (int p = 0; p < 5; ++p) {
            int ridx = tid + 256 * p;   // 0..1279 = jj*160+nu
            gload16(wsrc + (size_t)ridx * 8, &Bs[ridx * 8]);
        }
        __syncthreads();
        #pragma unroll
        for (int s = 0; s < 2; ++s) {
            int jj = s * 4 + q;
            bf16x8 av = *reinterpret_cast<const bf16x8*>(
                &As[(jj * 32 + mfrag * 16 + l16) << 3]);
            #pragma unroll
            for (int nt = 0; nt < 5; ++nt) {
                bf16x8 bv = *reinterpret_cast<const bf16x8*>(
                    &Bs[(jj * 160 + (ntb + nt) * 16 + l16) << 3]);
                acc[nt] = __builtin_amdgcn_mfma_f32_16x16x32_bf16(av, bv, acc[nt], 0, 0, 0);
            }
        }
    }
    float* dst = s_part + (size_t)(kb * 8 + mt) * 5120;
    #pragma unroll
    for (int nt = 0; nt < 5; ++nt)
        #pragma unroll
        for (int reg = 0; reg < 4; ++reg)
            dst[(mfrag * 16 + q * 4 + reg) * 160 + (ntb + nt) * 16 + l16] = acc[nt][reg];
}

// ---------------- fused reduce (36 slices) + normalize + squash ----------
__global__ void __launch_bounds__(320, 2)
k_reduce_s(const float* __restrict__ s_part, float* __restrict__ vdst,
           const float* __restrict__ expsum, int t0) {
    const int b = blockIdx.x, tid = threadIdx.x;
    const int t = tid % 160, kq = tid / 160;
    const int mt = b >> 5, bl = b & 31;
    const size_t off = (size_t)mt * 5120 + bl * 160 + t;

    __shared__ float invn[NN];
    if (tid < NN) invn[tid] = t0 ? (1.f / (float)JC) : 1.f / expsum[tid];

    float s = 0.f;
    for (int r = 0; r < 18; ++r)
        s += s_part[(size_t)(kq * 18 + r) * 40960 + off];

    __shared__ float red[2][160];
    __shared__ float sv[NU];
    __shared__ float fb[UU];
    red[kq][t] = s;
    __syncthreads();
    if (tid < NU) sv[tid] = (red[0][tid] + red[1][tid]) * invn[tid >> 4];
    __syncthreads();
    if (tid < UU) {
        float m = 0.f;
        #pragma unroll
        for (int n = 0; n < NN; ++n) { float z = sv[n*16 + tid]; m = fmaf(z, z, m); }
        fb[tid] = sqrtf(m) / (1.f + m);
    }
    __syncthreads();
    if (tid < NU)
        vdst[(size_t)b * NU + tid] = sv[tid] * fb[tid & 15];
}

// ---------------- fused routing: G-tile in LDS + d + softmax + e*W -------
// Block (jt 0..35, ng 0..4): j-range 32, n-range 2 (nu m-range 32), full
// K = 256 (batch). Per i-chunk (8): G-tile[32 m][32 j] computed via hi/lo
// bf16 3-MFMA (identical arithmetic to old k_vxg), dumped to LDS, then
// contracted with W into d-partials. No global G, no cross-block sync.
// Epilogue per block: d -> blog RMW, e=exp, expsum-bank atomicAdd,
// wbf[j-range, n-range] = bf16(e*W).
__global__ void __launch_bounds__(256)
k_route(const float* __restrict__ vg, const float* __restrict__ xg,
        const float* __restrict__ wg, float* __restrict__ blog,
        short* __restrict__ wbf, float* __restrict__ expsum, int t0) {
    const int jt = blockIdx.x, ng = blockIdx.y;
    const int j0 = jt * 32, n0 = ng * 2, m0 = n0 * 16;
    const int tid = threadIdx.x;
    const int wv = tid >> 6, lane = tid & 63;
    const int q = lane >> 4, l16 = lane & 15;
    const int mtl = wv >> 1, ntc = wv & 1;   // wave owns (m-tile, j-tile) quadrant

    __shared__ __align__(16) short Ash[8192], Asl[8192]; // [ks4][bhi8][ml32][blo8]
    __shared__ __align__(16) short Bsh[8192], Bsl[8192]; // [ks4][bhi8][jl32][blo8]
    __shared__ float Gt[32 * 32];
    __shared__ float red[256];
    __shared__ float esh[64];

    // stage v[0..255, m0..m0+32] hi/lo (once)
    #pragma unroll
    for (int p = 0; p < 32; ++p) {
        int e = tid + 256 * p;
        int b = e >> 5, ml = e & 31;
        float vv = vg[(size_t)b * NU + m0 + ml];
        short hi = f2bf(vv);
        short lo = f2bf(vv - bf2f(hi));
        int a = (b >> 6) * 2048 + (((b >> 3) & 7) * 32 + ml) * 8 + (b & 7);
        Ash[a] = hi; Asl[a] = lo;
    }

    float part = 0.f;
    for (int i = 0; i < 8; ++i) {
        __syncthreads();                 // Bs free (prev mfma done), Gt free
        // stage x[0..255, i, j0..j0+32] hi/lo
        #pragma unroll
        for (int p = 0; p < 32; ++p) {
            int e = tid + 256 * p;
            int b = e >> 5, jl = e & 31;
            float xv = xg[(size_t)b * NP + i * JC + j0 + jl];
            short hi = f2bf(xv);
            short lo = f2bf(xv - bf2f(hi));
            int a = (b >> 6) * 2048 + (((b >> 3) & 7) * 32 + jl) * 8 + (b & 7);
            Bsh[a] = hi; Bsl[a] = lo;
        }
        __syncthreads();
        f32x4 acc = (f32x4){0.f, 0.f, 0.f, 0.f};
        #pragma unroll
        for (int ks = 0; ks < 4; ++ks)
            #pragma unroll
            for (int s = 0; s < 2; ++s) {
                int kc = s * 4 + q;
                const int ai = ks * 2048 + (kc * 32 + mtl * 16 + l16) * 8;
                const int bi = ks * 2048 + (kc * 32 + ntc * 16 + l16) * 8;
                bf16x8 ah = *reinterpret_cast<const bf16x8*>(&Ash[ai]);
                bf16x8 al = *reinterpret_cast<const bf16x8*>(&Asl[ai]);
                bf16x8 bh = *reinterpret_cast<const bf16x8*>(&Bsh[bi]);
                bf16x8 bl = *reinterpret_cast<const bf16x8*>(&Bsl[bi]);
                acc = __builtin_amdgcn_mfma_f32_16x16x32_bf16(ah, bh, acc, 0, 0, 0);
                acc = __builtin_amdgcn_mfma_f32_16x16x32_bf16(ah, bl, acc, 0, 0, 0);
                acc = __builtin_amdgcn_mfma_f32_16x16x32_bf16(al, bh, acc, 0, 0, 0);
            }
        __syncthreads();                 // prior contract finished reading Gt
        #pragma unroll
        for (int r = 0; r < 4; ++r)      // C-layout: row=q*4+r, col=l16
            Gt[(mtl * 16 + q * 4 + r) * 32 + ntc * 16 + l16] = acc[r];
        __syncthreads();
        {   // contract: thread = (jl, nn, uq); d += G[nn*16+u][jl]*W[j,n,u,i]
            int jl = tid & 31, rr = tid >> 5;
            int nn = rr >> 2, uq = rr & 3;
            const float* wrow = wg + (size_t)(j0 + jl) * WROW + (n0 + nn) * 128 + i;
            #pragma unroll
            for (int k = 0; k < 4; ++k)
                part = fmaf(Gt[(nn * 16 + uq * 4 + k) * 32 + jl],
                            wrow[(uq * 4 + k) * 8], part);
        }
    }
    {   // fold partials over uq
        int jl = tid & 31, rr = tid >> 5;
        red[((rr >> 2) * 32 + jl) * 4 + (rr & 3)] = part;
    }
    __syncthreads();
    if (tid < 64) {                      // wave 0: finalize d, blog, exp
        int jl = tid & 31, nn = tid >> 5;
        int ri = (nn * 32 + jl) * 4;
        float d = (red[ri] + red[ri + 1] + red[ri + 2] + red[ri + 3])
                  * (1.f / (float)B);
        int bi = (j0 + jl) * NN + n0 + nn;
        float nb = t0 ? d : (blog[bi] + d);
        blog[bi] = nb;
        float e = __expf(nb);
        esh[jl * 2 + nn] = e;
        float ssum = e;
        ssum += __shfl_xor(ssum, 1);  ssum += __shfl_xor(ssum, 2);
        ssum += __shfl_xor(ssum, 4);  ssum += __shfl_xor(ssum, 8);
        ssum += __shfl_xor(ssum, 16);
        if ((tid & 31) == 0) atomicAdd(&expsum[n0 + nn], ssum);
    }
    __syncthreads();
    {   // wbf[j0+row][n0*128 + seg*32 ..+32] = bf16(e * W), reg-direct
        int row = tid >> 3, seg = tid & 7;
        float e = esh[row * 2 + (seg >> 2)];
        const float4* wp = reinterpret_cast<const float4*>(
            wg + (size_t)(j0 + row) * WROW + n0 * 128 + seg * 32);
        short* dst = wbf + (size_t)(j0 + row) * WROW + n0 * 128 + seg * 32;
        #pragma unroll
        for (int k2 = 0; k2 < 4; ++k2) {
            float4 f0 = wp[k2 * 2], f1 = wp[k2 * 2 + 1];
            uint4 dd;
            dd.x = pk2(f0.x * e, f0.y * e); dd.y = pk2(f0.z * e, f0.w * e);
            dd.z = pk2(f1.x * e, f1.y * e); dd.w = pk2(f1.z * e, f1.w * e);
            *reinterpret_cast<uint4*>(&dst[k2 * 8]) = dd;
        }
    }
}

extern "C" void kernel_launch(void* const* d_in, const int* in_sizes, int n_in,
                              void* d_out, int out_size, void* d_ws, size_t ws_size,
                              hipStream_t stream) {
    const float* x = (const float*)d_in[0];
    const float* w = (const float*)d_in[1];
    float* out = (float*)d_out;

    float* ws     = (float*)d_ws;
    float* blog   = ws;                           // 11520 f
    float* expsum = blog + JN;                    // 32 f (2 banks of 16)
    float* v      = expsum + 32;                  // 40960 f
    short* wbf    = (short*)(v + (size_t)B * NU); // 1,474,560 bf16 (2.95 MB)
    short* xbf    = wbf + (size_t)JC * WROW;      // 2,359,296 bf16 (4.72 MB)
    float* s_part = (float*)(xbf + (size_t)JC * 2048); // 36*40960 f (5.9 MB)
    // total ≈ 13.8 MB; G eliminated

    k_prep<<<1296, 256, 0, stream>>>(x, w, wbf, xbf, expsum);
    for (int t = 0; t < 3; ++t) {
        k_gemm1<<<dim3(KB, 8), 256, 0, stream>>>(xbf, wbf, s_part);
        k_reduce_s<<<B, 320, 0, stream>>>(
            s_part, (t == 2) ? out : v,
            expsum + ((t == 0) ? 0 : (t - 1) * 16), (t == 0) ? 1 : 0);
        if (t < 2)
            k_route<<<dim3(36, 5), 256, 0, stream>>>(
                v, x, w, blog, wbf, expsum + t * 16, (t == 0) ? 1 : 0);
    }
}